// Round 11
// baseline (470.168 us; speedup 1.0000x reference)
//
#include <hip/hip_runtime.h>
#include <hip/hip_cooperative_groups.h>
#include <hip/hip_bf16.h>

namespace cg = cooperative_groups;

#define NN 3072
#define CCC 16
#define HH 128
#define KTOP 4
#define NCLS 455   // C(15,3)
#define NUP 120
#define EPSF 1e-5f

// ---------------- ws layout (float offsets) ----------------
#define OFF_F       0
#define SZ_F        (16*NCLS*HH)
#define OFF_CNT     (OFF_F + SZ_F)
#define SZ_CNT      (16*NCLS)
#define OFF_SUMS    (OFF_CNT + SZ_CNT)
#define SZ_SUMS     32
#define OFF_NCNT    (OFF_SUMS + SZ_SUMS)
#define SZ_NCNT     256
#define ZERO_FLOATS (OFF_NCNT + SZ_NCNT)
#define OFF_LOGITS  ZERO_FLOATS
#define SZ_LOGITS   (NN*CCC)
#define OFF_COLS    (OFF_LOGITS + SZ_LOGITS)
#define SZ_E        (NN*KTOP)
#define OFF_RANKS   (OFF_COLS + SZ_E)
#define OFF_FISEL   (OFF_RANKS + SZ_E)
#define OFF_NLIST   (OFF_FISEL + SZ_E)
#define SZ_NLIST    (16*NN)
#define OFF_UP      (OFF_NLIST + SZ_NLIST)
#define SZ_UP       (16*NUP*HH)
#define OFF_AGG     (OFF_UP + SZ_UP)
#define OFF_HC      (OFF_AGG + SZ_F)
#define SZ_HC       (NN*KTOP*HH)
#define OFF_HALF    (OFF_HC + SZ_HC)
#define HOFF_W1H    0
#define HOFF_W1L    16384
#define HOFF_WLH    32768
#define HOFF_WRH    (32768 + 262144)
#define CVT_TOTAL   (16384 + 262144 + 262144)

#define MT 64

typedef _Float16 h8 __attribute__((ext_vector_type(8)));
typedef float    f4 __attribute__((ext_vector_type(4)));

__device__ __forceinline__ int C2i(int x){ return x*(x-1)/2; }
__device__ __forceinline__ int C3i(int x){ return x*(x-1)*(x-2)/6; }

__device__ __forceinline__ unsigned decode_mask(int r){
  int c = 2; while (c < 14 && C3i(c+1) <= r) c++;
  int rem = r - C3i(c);
  int b = 1; while (b < c-1 && C2i(b+1) <= rem) b++;
  int a = rem - C2i(b);
  return (1u<<a) | (1u<<b) | (1u<<c);
}

// ===================== persistent cooperative mega-kernel =====================
__global__ void __launch_bounds__(256)
k_all(const float* __restrict__ X, const float* __restrict__ W1,
      const float* __restrict__ b1, const float* __restrict__ ln_g,
      const float* __restrict__ ln_b, const float* __restrict__ W2,
      const float* __restrict__ b2, const float* __restrict__ Wl,
      const float* __restrict__ bl, const float* __restrict__ Wr,
      float* __restrict__ ws, float* __restrict__ outp){
  cg::grid_group grid = cg::this_grid();
  float* F      = ws + OFF_F;
  float* cnt    = ws + OFF_CNT;
  float* sums   = ws + OFF_SUMS;
  int*   nodeCnt= (int*)(ws + OFF_NCNT);
  float* logits = ws + OFF_LOGITS;
  int*   cols   = (int*)(ws + OFF_COLS);
  int*   ranks  = (int*)(ws + OFF_RANKS);
  float* fiSel  = ws + OFF_FISEL;
  int*   nodeList=(int*)(ws + OFF_NLIST);
  float* UP     = ws + OFF_UP;
  float* agg    = ws + OFF_AGG;
  float* hcBuf  = ws + OFF_HC;
  _Float16* hb  = (_Float16*)(ws + OFF_HALF);
  _Float16* W1h = hb + HOFF_W1H;
  _Float16* W1l = hb + HOFF_W1L;
  _Float16* Wlh = hb + HOFF_WLH;
  _Float16* Wrh = hb + HOFF_WRH;

  int t = threadIdx.x;
  int w = t >> 6, lane = t & 63;
  int l15 = lane & 15, quad = lane >> 4;
  int nb = gridDim.x;
  int gid = blockIdx.x*256 + t;
  int gsz = nb*256;

  __shared__ int lcnt[CCC], lbase[CCC];
  __shared__ unsigned tm[NCLS];
  __shared__ float rb[8];

  // ---------- S0: zero accumulators + convert weights to f16 ----------
  for (int i = gid; i < ZERO_FLOATS; i += gsz) ws[i] = 0.f;
  for (int i = gid; i < CVT_TOTAL; i += gsz){
    if (i < 16384){
      float x = W1[i]; _Float16 h = (_Float16)x;
      W1h[i] = h; W1l[i] = (_Float16)(x - (float)h);
    } else if (i < 16384 + 262144){
      Wlh[i-16384] = (_Float16)Wl[i-16384];
    } else {
      Wrh[i-16384-262144] = (_Float16)Wr[i-16384-262144];
    }
  }
  grid.sync();

  // ---------- S1: logits (MFMA hi/lo split) ----------
  for (int tile = blockIdx.x; tile < NN*CCC/MT; tile += nb){
    int base = tile*MT;
    int mA = base + 16*w + l15;
    const float* xrow = X + (size_t)mA*HH;
    h8 ah[4], al[4];
    #pragma unroll
    for (int c=0;c<4;++c){
      float4 u = *(const float4*)(xrow + c*32 + quad*8);
      float4 v = *(const float4*)(xrow + c*32 + quad*8 + 4);
      float xv[8] = {u.x,u.y,u.z,u.w,v.x,v.y,v.z,v.w};
      #pragma unroll
      for (int j=0;j<8;++j){
        _Float16 hi = (_Float16)xv[j];
        ah[c][j] = hi;
        al[c][j] = (_Float16)(xv[j] - (float)hi);
      }
    }
    f4 acc[8];
    #pragma unroll
    for (int nt=0;nt<8;++nt) acc[nt] = (f4){0.f,0.f,0.f,0.f};
    #pragma unroll
    for (int c=0;c<4;++c){
      #pragma unroll
      for (int nt=0;nt<8;++nt){
        int o = nt*16 + l15;
        h8 bh  = *(const h8*)(W1h + (size_t)o*HH + c*32 + quad*8);
        h8 bl_ = *(const h8*)(W1l + (size_t)o*HH + c*32 + quad*8);
        acc[nt] = __builtin_amdgcn_mfma_f32_16x16x32_f16(ah[c], bh,  acc[nt], 0,0,0);
        acc[nt] = __builtin_amdgcn_mfma_f32_16x16x32_f16(al[c], bh,  acc[nt], 0,0,0);
        acc[nt] = __builtin_amdgcn_mfma_f32_16x16x32_f16(ah[c], bl_, acc[nt], 0,0,0);
        acc[nt] = __builtin_amdgcn_mfma_f32_16x16x32_f16(al[c], bl_, acc[nt], 0,0,0);
      }
    }
    float bv[8], gv[8], lv[8], wv[8];
    #pragma unroll
    for (int nt=0;nt<8;++nt){
      int o = nt*16 + l15;
      bv[nt]=b1[o]; gv[nt]=ln_g[o]; lv[nt]=ln_b[o]; wv[nt]=W2[o];
    }
    float b2v = b2[0];
    #pragma unroll
    for (int r=0;r<4;++r){
      float z[8];
      float s1=0.f, s2=0.f;
      #pragma unroll
      for (int nt=0;nt<8;++nt){
        float zz = acc[nt][r] + bv[nt];
        zz = zz>0.f ? zz : 0.f;
        z[nt] = zz; s1 += zz; s2 += zz*zz;
      }
      #pragma unroll
      for (int m=1;m<16;m<<=1){ s1 += __shfl_xor(s1,m); s2 += __shfl_xor(s2,m); }
      float mu = s1/(float)HH;
      float var = s2/(float)HH - mu*mu;
      float rs = 1.0f/sqrtf(var+EPSF);
      float s3 = 0.f;
      #pragma unroll
      for (int nt=0;nt<8;++nt){
        float zn = (z[nt]-mu)*rs*gv[nt] + lv[nt];
        s3 += zn*wv[nt];
      }
      #pragma unroll
      for (int m=1;m<16;m<<=1) s3 += __shfl_xor(s3,m);
      if (l15 == 0) logits[base + 16*w + quad*4 + r] = s3 + b2v;
    }
  }
  grid.sync();

  // ---------- S2: softmax + top-4 + class ranks + node lists ----------
  for (int tile = blockIdx.x; tile < NN/256; tile += nb){
    if (t < CCC) lcnt[t] = 0;
    __syncthreads();
    int n = tile*256 + t;
    float l[CCC];
    #pragma unroll
    for (int c=0;c<CCC;++c) l[c] = logits[n*CCC+c];
    unsigned mask = 0;
    #pragma unroll
    for (int k=0;k<KTOP;++k){
      float best = -3e38f; int bi = 0;
      #pragma unroll
      for (int c=0;c<CCC;++c){
        bool taken = (mask>>c)&1u;
        if (!taken && l[c] > best){ best = l[c]; bi = c; }
      }
      mask |= 1u<<bi;
    }
    float m = -3e38f;
    #pragma unroll
    for (int c=0;c<CCC;++c) m = l[c]>m ? l[c] : m;
    float s = 0.f;
    #pragma unroll
    for (int c=0;c<CCC;++c) s += expf(l[c]-m);
    float inv = 1.0f/s;
    int mycis[KTOP], mypos[KTOP];
    unsigned m2 = mask;
    for (int j=0;j<KTOP;++j){
      int ci = __ffs(m2)-1; m2 &= m2-1u;
      unsigned rest = mask & ~(1u<<ci);
      int v[3]; unsigned r2 = rest;
      #pragma unroll
      for (int q=0;q<3;++q){ int col = __ffs(r2)-1; r2 &= r2-1u; v[q] = col - (col>ci ? 1:0); }
      int rank = C3i(v[2]) + C2i(v[1]) + v[0];
      int e4 = n*KTOP + j;
      cols[e4] = ci; ranks[e4] = rank;
      fiSel[e4] = expf(l[ci]-m)*inv;
      mycis[j] = ci;
      mypos[j] = atomicAdd(&lcnt[ci], 1);
    }
    __syncthreads();
    if (t < CCC) lbase[t] = atomicAdd(&nodeCnt[t*16], lcnt[t]);
    __syncthreads();
    #pragma unroll
    for (int j=0;j<KTOP;++j){
      int ci = mycis[j];
      nodeList[ci*NN + lbase[ci] + mypos[j]] = n*KTOP + j;
    }
    __syncthreads();
  }
  grid.sync();

  // ---------- S3: class feature sums (global atomics) ----------
  for (int u = blockIdx.x; u < NN*KTOP/2; u += nb){
    int e = u*2 + (t>>7);
    int h = t & 127;
    int ci = cols[e], rank = ranks[e];
    float fi = fiSel[e];
    int n = e >> 2;
    float v = X[(n*CCC+ci)*HH + h] * fi;
    atomicAdd(&F[(ci*NCLS+rank)*HH + h], v);
    if (h==0) atomicAdd(&cnt[ci*NCLS+rank], 1.0f);
  }
  grid.sync();

  // ---------- S4: pairs P_xy = sum_z F[{x,y,z}]  (wave per unit) ----------
  for (int u = blockIdx.x*4 + w; u < 105*CCC; u += nb*4){
    int p = u % 105, ci = u / 105;
    int pb_ = 1; while (pb_ < 14 && C2i(pb_+1) <= p) pb_++;
    int pa_ = p - C2i(pb_);
    const float* Fc = F + (size_t)ci*NCLS*HH;
    int col = lane*2;
    float a0 = 0.f, a1 = 0.f;
    #pragma unroll
    for (int z = 0; z < 15; ++z){
      if (z == pa_ || z == pb_) continue;
      int lo, mid, hi;
      if (z < pa_){ lo = z;  mid = pa_; hi = pb_; }
      else if (z < pb_){ lo = pa_; mid = z;  hi = pb_; }
      else { lo = pa_; mid = pb_; hi = z; }
      float2 v = *(const float2*)&Fc[(size_t)(C3i(hi)+C2i(mid)+lo)*HH + col];
      a0 += v.x; a1 += v.y;
    }
    float2 o2 = {a0, a1};
    *(float2*)&UP[((size_t)ci*NUP + 15 + p)*HH + col] = o2;
  }
  grid.sync();

  // ---------- S5: singles U_x = 0.5 * sum_{y!=x} P_xy ----------
  for (int u = blockIdx.x*4 + w; u < 15*CCC; u += nb*4){
    int x = u % 15, ci = u / 15;
    const float* Pc = UP + ((size_t)ci*NUP + 15)*HH;
    int col = lane*2;
    float a0 = 0.f, a1 = 0.f;
    #pragma unroll
    for (int y = 0; y < 15; ++y){
      if (y == x) continue;
      int lo = x < y ? x : y, hi = x < y ? y : x;
      float2 v = *(const float2*)&Pc[(size_t)(C2i(hi)+lo)*HH + col];
      a0 += v.x; a1 += v.y;
    }
    float2 o2 = {0.5f*a0, 0.5f*a1};
    *(float2*)&UP[((size_t)ci*NUP + x)*HH + col] = o2;
  }
  grid.sync();

  // ---------- S6: agg via inclusion-exclusion + degree ----------
  for (int i=t;i<NCLS;i+=256) tm[i] = decode_mask(i);
  __syncthreads();
  for (int u = blockIdx.x*4 + w; u < NCLS*CCC; u += nb*4){
    int r = u % NCLS, ci = u / NCLS;
    unsigned m = tm[r];
    float d = 0.f;
    const float* cc = cnt + ci*NCLS;
    for (int tp=lane; tp<NCLS; tp+=64)
      if (m & tm[tp]) d += cc[tp];
    #pragma unroll
    for (int mm=1; mm<64; mm<<=1) d += __shfl_xor(d, mm);
    float invd = 1.0f / fmaxf(d, 1.0f);
    int c = 2; while (c < 14 && C3i(c+1) <= r) c++;
    int rem = r - C3i(c);
    int b = 1; while (b < c-1 && C2i(b+1) <= rem) b++;
    int a = rem - C2i(b);
    const float* U = UP + (size_t)ci*NUP*HH;
    int pab = 15 + C2i(b) + a;
    int pac = 15 + C2i(c) + a;
    int pbc = 15 + C2i(c) + b;
    int col = lane*2;
    float2 ua = *(const float2*)&U[(size_t)a*HH+col];
    float2 ub = *(const float2*)&U[(size_t)b*HH+col];
    float2 uc = *(const float2*)&U[(size_t)c*HH+col];
    float2 p1 = *(const float2*)&U[(size_t)pab*HH+col];
    float2 p2 = *(const float2*)&U[(size_t)pac*HH+col];
    float2 p3 = *(const float2*)&U[(size_t)pbc*HH+col];
    float2 ff = *(const float2*)&F[((size_t)ci*NCLS+r)*HH+col];
    float2 o2;
    o2.x = (ua.x+ub.x+uc.x-p1.x-p2.x-p3.x+ff.x)*invd;
    o2.y = (ua.y+ub.y+uc.y-p1.y-p2.y-p3.y+ff.y)*invd;
    *(float2*)&agg[((size_t)ci*NCLS+r)*HH + col] = o2;
  }
  grid.sync();

  // ---------- S7: AggWl = Agg @ Wl^T + bl  (in-place, f16 MFMA) ----------
  for (int tile = blockIdx.x; tile < 8*CCC; tile += nb){
    int ci = tile & 15, base = (tile >> 4)*MT;
    int rowA = base + 16*w + l15; if (rowA > NCLS-1) rowA = NCLS-1;
    const float* arow = agg + ((size_t)ci*NCLS + rowA)*HH;
    h8 af[4];
    #pragma unroll
    for (int c=0;c<4;++c){
      float4 u = *(const float4*)(arow + c*32 + quad*8);
      float4 v = *(const float4*)(arow + c*32 + quad*8 + 4);
      float xv[8] = {u.x,u.y,u.z,u.w,v.x,v.y,v.z,v.w};
      #pragma unroll
      for (int j=0;j<8;++j) af[c][j] = (_Float16)xv[j];
    }
    f4 acc[8];
    #pragma unroll
    for (int nt=0;nt<8;++nt) acc[nt] = (f4){0.f,0.f,0.f,0.f};
    const _Float16* Wc = Wlh + (size_t)ci*HH*HH;
    #pragma unroll
    for (int c=0;c<4;++c){
      #pragma unroll
      for (int nt=0;nt<8;++nt){
        int o = nt*16 + l15;
        h8 bh = *(const h8*)(Wc + (size_t)o*HH + c*32 + quad*8);
        acc[nt] = __builtin_amdgcn_mfma_f32_16x16x32_f16(af[c], bh, acc[nt], 0,0,0);
      }
    }
    #pragma unroll
    for (int r=0;r<4;++r){
      int row2 = base + 16*w + quad*4 + r;
      if (row2 < NCLS){
        float* drow = agg + ((size_t)ci*NCLS + row2)*HH;
        #pragma unroll
        for (int nt=0;nt<8;++nt){
          int o = nt*16 + l15;
          drow[o] = acc[nt][r] + bl[ci*HH + o];
        }
      }
    }
  }
  grid.sync();

  // ---------- S8: hc = relu(AggWl[class] + fi*X @ Wr^T)  (f16 MFMA) ----------
  for (int tile = blockIdx.x; tile < (NN/MT)*CCC; tile += nb){
    int ci = tile & 15, base = (tile >> 4)*MT;
    int cntc = nodeCnt[ci*16];
    if (base < cntc){
      int pA = base + 16*w + l15;
      float fi = 0.f; int nA = 0;
      if (pA < cntc){
        int e = nodeList[ci*NN + pA];
        fi = fiSel[e]; nA = e >> 2;
      }
      const float* xrow = X + ((size_t)nA*CCC + ci)*HH;
      h8 af[4];
      #pragma unroll
      for (int c=0;c<4;++c){
        float4 u = *(const float4*)(xrow + c*32 + quad*8);
        float4 v = *(const float4*)(xrow + c*32 + quad*8 + 4);
        float xv[8] = {u.x,u.y,u.z,u.w,v.x,v.y,v.z,v.w};
        #pragma unroll
        for (int j=0;j<8;++j) af[c][j] = (_Float16)(xv[j]*fi);
      }
      f4 acc[8];
      #pragma unroll
      for (int nt=0;nt<8;++nt) acc[nt] = (f4){0.f,0.f,0.f,0.f};
      const _Float16* Wc = Wrh + (size_t)ci*HH*HH;
      #pragma unroll
      for (int c=0;c<4;++c){
        #pragma unroll
        for (int nt=0;nt<8;++nt){
          int o = nt*16 + l15;
          h8 bh = *(const h8*)(Wc + (size_t)o*HH + c*32 + quad*8);
          acc[nt] = __builtin_amdgcn_mfma_f32_16x16x32_f16(af[c], bh, acc[nt], 0,0,0);
        }
      }
      float s1 = 0.f, s2 = 0.f;
      #pragma unroll
      for (int r=0;r<4;++r){
        int pD = base + 16*w + quad*4 + r;
        int e2 = -1, rk2 = 0;
        if (pD < cntc){ e2 = nodeList[ci*NN + pD]; rk2 = ranks[e2]; }
        if (e2 >= 0){
          const float* G = agg + ((size_t)ci*NCLS + rk2)*HH;
          float* drow = hcBuf + (size_t)e2*HH;
          #pragma unroll
          for (int nt=0;nt<8;++nt){
            int o = nt*16 + l15;
            float vv = acc[nt][r] + G[o];
            vv = vv>0.f ? vv : 0.f;
            drow[o] = vv;
            s1 += vv; s2 += vv*vv;
          }
        }
      }
      #pragma unroll
      for (int m=1;m<64;m<<=1){ s1 += __shfl_xor(s1,m); s2 += __shfl_xor(s2,m); }
      if (lane == 0){ rb[w] = s1; rb[4+w] = s2; }
      __syncthreads();
      if (t==0){
        atomicAdd(&sums[ci],    rb[0]+rb[1]+rb[2]+rb[3]);
        atomicAdd(&sums[16+ci], rb[4]+rb[5]+rb[6]+rb[7]);
      }
      __syncthreads();
    }
  }
  grid.sync();

  // ---------- S9: masked mean/var normalize, write output ----------
  for (int idx = gid; idx < NN*KTOP*HH; idx += gsz){
    int e = idx >> 7;
    int ci = cols[e];
    float cntf = (float)nodeCnt[ci*16];
    float nel = fmaxf(cntf * (float)HH, 1.0f);
    float mu = sums[ci]/nel;
    float var = sums[16+ci]/nel - mu*mu;
    outp[idx] = (hcBuf[idx]-mu)/sqrtf(var+EPSF);
  }
}

// ===================== fallback: R9 ten-kernel pipeline =====================
__global__ __launch_bounds__(256) void k_cvt(const float* __restrict__ W1,
    const float* __restrict__ Wl, const float* __restrict__ Wr,
    _Float16* __restrict__ hbase, float* __restrict__ ws){
  int i = blockIdx.x*256 + threadIdx.x;
  if (i < ZERO_FLOATS) ws[i] = 0.f;
  if (i < 16384){
    float x = W1[i];
    _Float16 h = (_Float16)x;
    hbase[HOFF_W1H + i] = h;
    hbase[HOFF_W1L + i] = (_Float16)(x - (float)h);
  }
  int j = i - 16384;
  if (j >= 0 && j < 262144) hbase[HOFF_WLH + j] = (_Float16)Wl[j];
  int k2 = i - (16384 + 262144);
  if (k2 >= 0 && k2 < 262144) hbase[HOFF_WRH + k2] = (_Float16)Wr[k2];
}

__global__ __launch_bounds__(256) void k_logits(const float* __restrict__ X,
    const _Float16* __restrict__ W1h, const _Float16* __restrict__ W1l,
    const float* __restrict__ b1, const float* __restrict__ ln_g,
    const float* __restrict__ ln_b, const float* __restrict__ W2,
    const float* __restrict__ b2, float* __restrict__ logits){
  int t = threadIdx.x;
  int w = t >> 6;
  int lane = t & 63;
  int l15 = lane & 15, quad = lane >> 4;
  int base = blockIdx.x * MT;
  int mA = base + 16*w + l15;
  const float* xrow = X + (size_t)mA*HH;
  h8 ah[4], al[4];
  #pragma unroll
  for (int c=0;c<4;++c){
    float4 u = *(const float4*)(xrow + c*32 + quad*8);
    float4 v = *(const float4*)(xrow + c*32 + quad*8 + 4);
    float xv[8] = {u.x,u.y,u.z,u.w,v.x,v.y,v.z,v.w};
    #pragma unroll
    for (int j=0;j<8;++j){
      _Float16 hi = (_Float16)xv[j];
      ah[c][j] = hi;
      al[c][j] = (_Float16)(xv[j] - (float)hi);
    }
  }
  f4 acc[8];
  #pragma unroll
  for (int nt=0;nt<8;++nt) acc[nt] = (f4){0.f,0.f,0.f,0.f};
  #pragma unroll
  for (int c=0;c<4;++c){
    #pragma unroll
    for (int nt=0;nt<8;++nt){
      int o = nt*16 + l15;
      h8 bh  = *(const h8*)(W1h + (size_t)o*HH + c*32 + quad*8);
      h8 bl_ = *(const h8*)(W1l + (size_t)o*HH + c*32 + quad*8);
      acc[nt] = __builtin_amdgcn_mfma_f32_16x16x32_f16(ah[c], bh,  acc[nt], 0,0,0);
      acc[nt] = __builtin_amdgcn_mfma_f32_16x16x32_f16(al[c], bh,  acc[nt], 0,0,0);
      acc[nt] = __builtin_amdgcn_mfma_f32_16x16x32_f16(ah[c], bl_, acc[nt], 0,0,0);
      acc[nt] = __builtin_amdgcn_mfma_f32_16x16x32_f16(al[c], bl_, acc[nt], 0,0,0);
    }
  }
  float bv[8], gv[8], lv[8], wv[8];
  #pragma unroll
  for (int nt=0;nt<8;++nt){
    int o = nt*16 + l15;
    bv[nt]=b1[o]; gv[nt]=ln_g[o]; lv[nt]=ln_b[o]; wv[nt]=W2[o];
  }
  float b2v = b2[0];
  #pragma unroll
  for (int r=0;r<4;++r){
    float z[8];
    float s1=0.f, s2=0.f;
    #pragma unroll
    for (int nt=0;nt<8;++nt){
      float zz = acc[nt][r] + bv[nt];
      zz = zz>0.f ? zz : 0.f;
      z[nt] = zz; s1 += zz; s2 += zz*zz;
    }
    #pragma unroll
    for (int m=1;m<16;m<<=1){ s1 += __shfl_xor(s1,m); s2 += __shfl_xor(s2,m); }
    float mu = s1/(float)HH;
    float var = s2/(float)HH - mu*mu;
    float rs = 1.0f/sqrtf(var+EPSF);
    float s3 = 0.f;
    #pragma unroll
    for (int nt=0;nt<8;++nt){
      float zn = (z[nt]-mu)*rs*gv[nt] + lv[nt];
      s3 += zn*wv[nt];
    }
    #pragma unroll
    for (int m=1;m<16;m<<=1) s3 += __shfl_xor(s3,m);
    if (l15 == 0) logits[base + 16*w + quad*4 + r] = s3 + b2v;
  }
}

__global__ __launch_bounds__(256) void k_topk(const float* __restrict__ logits,
    int* __restrict__ cols, int* __restrict__ ranks, float* __restrict__ fiSel,
    int* __restrict__ nodeCnt, int* __restrict__ nodeList){
  __shared__ int lcnt[CCC];
  __shared__ int lbase[CCC];
  int t = threadIdx.x;
  if (t < CCC) lcnt[t] = 0;
  __syncthreads();
  int n = blockIdx.x*256 + t;
  float l[CCC];
  #pragma unroll
  for (int c=0;c<CCC;++c) l[c] = logits[n*CCC+c];
  unsigned mask = 0;
  #pragma unroll
  for (int k=0;k<KTOP;++k){
    float best = -3e38f; int bi = 0;
    #pragma unroll
    for (int c=0;c<CCC;++c){
      bool taken = (mask>>c)&1u;
      if (!taken && l[c] > best){ best = l[c]; bi = c; }
    }
    mask |= 1u<<bi;
  }
  float m = -3e38f;
  #pragma unroll
  for (int c=0;c<CCC;++c) m = l[c]>m ? l[c] : m;
  float s = 0.f;
  #pragma unroll
  for (int c=0;c<CCC;++c) s += expf(l[c]-m);
  float inv = 1.0f/s;
  int mycis[KTOP], mypos[KTOP];
  unsigned m2 = mask;
  for (int j=0;j<KTOP;++j){
    int ci = __ffs(m2)-1; m2 &= m2-1u;
    unsigned rest = mask & ~(1u<<ci);
    int v[3]; unsigned r2 = rest;
    #pragma unroll
    for (int q=0;q<3;++q){ int col = __ffs(r2)-1; r2 &= r2-1u; v[q] = col - (col>ci ? 1:0); }
    int rank = C3i(v[2]) + C2i(v[1]) + v[0];
    int e4 = n*KTOP + j;
    cols[e4] = ci; ranks[e4] = rank;
    fiSel[e4] = expf(l[ci]-m)*inv;
    mycis[j] = ci;
    mypos[j] = atomicAdd(&lcnt[ci], 1);
  }
  __syncthreads();
  if (t < CCC) lbase[t] = atomicAdd(&nodeCnt[t*16], lcnt[t]);
  __syncthreads();
  #pragma unroll
  for (int j=0;j<KTOP;++j){
    int ci = mycis[j];
    nodeList[ci*NN + lbase[ci] + mypos[j]] = n*KTOP + j;
  }
}

__global__ __launch_bounds__(256) void k_accF(const float* __restrict__ X,
    const int* __restrict__ cols, const int* __restrict__ ranks,
    const float* __restrict__ fiSel, float* __restrict__ F, float* __restrict__ cnt){
  int e = blockIdx.x*2 + (threadIdx.x>>7);
  int h = threadIdx.x & 127;
  int ci = cols[e], rank = ranks[e];
  float fi = fiSel[e];
  int n = e >> 2;
  float v = X[(n*CCC+ci)*HH + h] * fi;
  atomicAdd(&F[(ci*NCLS+rank)*HH + h], v);
  if (h==0) atomicAdd(&cnt[ci*NCLS+rank], 1.0f);
}

__global__ __launch_bounds__(128) void k_pairs(const float* __restrict__ F, float* __restrict__ UP){
  int t = threadIdx.x;
  int p = blockIdx.x, ci = blockIdx.y;
  int pb = 1; while (pb < 14 && C2i(pb+1) <= p) pb++;
  int pa = p - C2i(pb);
  const float* Fc = F + (size_t)ci*NCLS*HH;
  float acc = 0.f;
  #pragma unroll
  for (int z = 0; z < 15; ++z){
    if (z == pa || z == pb) continue;
    int lo, mid, hi;
    if (z < pa){ lo = z;  mid = pa; hi = pb; }
    else if (z < pb){ lo = pa; mid = z;  hi = pb; }
    else { lo = pa; mid = pb; hi = z; }
    int rank = C3i(hi) + C2i(mid) + lo;
    acc += Fc[(size_t)rank*HH + t];
  }
  UP[((size_t)ci*NUP + 15 + p)*HH + t] = acc;
}

__global__ __launch_bounds__(128) void k_singles(float* __restrict__ UP){
  int t = threadIdx.x;
  int x = blockIdx.x, ci = blockIdx.y;
  const float* Pc = UP + ((size_t)ci*NUP + 15)*HH;
  float acc = 0.f;
  #pragma unroll
  for (int y = 0; y < 15; ++y){
    if (y == x) continue;
    int lo = x < y ? x : y, hi = x < y ? y : x;
    int pi = C2i(hi) + lo;
    acc += Pc[(size_t)pi*HH + t];
  }
  UP[((size_t)ci*NUP + x)*HH + t] = 0.5f*acc;
}

__global__ __launch_bounds__(128) void k_as(const float* __restrict__ F,
    const float* __restrict__ UP, const float* __restrict__ cnt, float* __restrict__ agg){
  __shared__ unsigned tm[NCLS];
  __shared__ float dred[2];
  int t = threadIdx.x;
  for (int i=t;i<NCLS;i+=128) tm[i] = decode_mask(i);
  __syncthreads();
  int r = blockIdx.x, ci = blockIdx.y;
  unsigned m = tm[r];
  float d = 0.f;
  const float* cc = cnt + ci*NCLS;
  for (int tp=t; tp<NCLS; tp+=128)
    if (m & tm[tp]) d += cc[tp];
  #pragma unroll
  for (int mm=1; mm<64; mm<<=1) d += __shfl_xor(d, mm);
  if ((t&63)==0) dred[t>>6] = d;
  __syncthreads();
  float invd = 1.0f / fmaxf(dred[0]+dred[1], 1.0f);
  int c = 2; while (c < 14 && C3i(c+1) <= r) c++;
  int rem = r - C3i(c);
  int b = 1; while (b < c-1 && C2i(b+1) <= rem) b++;
  int a = rem - C2i(b);
  const float* U = UP + ci*NUP*HH;
  int pab = 15 + C2i(b) + a;
  int pac = 15 + C2i(c) + a;
  int pbc = 15 + C2i(c) + b;
  float v = U[a*HH+t] + U[b*HH+t] + U[c*HH+t]
          - U[pab*HH+t] - U[pac*HH+t] - U[pbc*HH+t]
          + F[(ci*NCLS+r)*HH + t];
  agg[(ci*NCLS+r)*HH + t] = v * invd;
}

__global__ __launch_bounds__(256) void k_aggwl(float* __restrict__ agg,
    const _Float16* __restrict__ Wlh, const float* __restrict__ bl){
  int t = threadIdx.x;
  int w = t >> 6;
  int lane = t & 63;
  int l15 = lane & 15, quad = lane >> 4;
  int ci = blockIdx.y;
  int base = blockIdx.x * MT;
  int rowA = base + 16*w + l15; if (rowA > NCLS-1) rowA = NCLS-1;
  const float* arow = agg + ((size_t)ci*NCLS + rowA)*HH;
  h8 af[4];
  #pragma unroll
  for (int c=0;c<4;++c){
    float4 u = *(const float4*)(arow + c*32 + quad*8);
    float4 v = *(const float4*)(arow + c*32 + quad*8 + 4);
    float xv[8] = {u.x,u.y,u.z,u.w,v.x,v.y,v.z,v.w};
    #pragma unroll
    for (int j=0;j<8;++j) af[c][j] = (_Float16)xv[j];
  }
  f4 acc[8];
  #pragma unroll
  for (int nt=0;nt<8;++nt) acc[nt] = (f4){0.f,0.f,0.f,0.f};
  const _Float16* Wc = Wlh + (size_t)ci*HH*HH;
  #pragma unroll
  for (int c=0;c<4;++c){
    #pragma unroll
    for (int nt=0;nt<8;++nt){
      int o = nt*16 + l15;
      h8 bh = *(const h8*)(Wc + (size_t)o*HH + c*32 + quad*8);
      acc[nt] = __builtin_amdgcn_mfma_f32_16x16x32_f16(af[c], bh, acc[nt], 0,0,0);
    }
  }
  #pragma unroll
  for (int r=0;r<4;++r){
    int row2 = base + 16*w + quad*4 + r;
    if (row2 < NCLS){
      float* drow = agg + ((size_t)ci*NCLS + row2)*HH;
      #pragma unroll
      for (int nt=0;nt<8;++nt){
        int o = nt*16 + l15;
        drow[o] = acc[nt][r] + bl[ci*HH + o];
      }
    }
  }
}

__global__ __launch_bounds__(256) void k_hc2(const float* __restrict__ X,
    const _Float16* __restrict__ Wrh,
    const int* __restrict__ ranks, const float* __restrict__ fiSel,
    const int* __restrict__ nodeCnt, const int* __restrict__ nodeList,
    const float* __restrict__ aggwl, float* __restrict__ hcBuf, float* __restrict__ sums){
  int ci = blockIdx.y;
  int cntc = nodeCnt[ci*16];
  int base = blockIdx.x * MT;
  if (base >= cntc) return;
  __shared__ float rb[8];
  int t = threadIdx.x;
  int w = t >> 6;
  int lane = t & 63;
  int l15 = lane & 15, quad = lane >> 4;
  int pA = base + 16*w + l15;
  float fi = 0.f; int nA = 0;
  if (pA < cntc){
    int e = nodeList[ci*NN + pA];
    fi = fiSel[e]; nA = e >> 2;
  }
  const float* xrow = X + ((size_t)nA*CCC + ci)*HH;
  h8 af[4];
  #pragma unroll
  for (int c=0;c<4;++c){
    float4 u = *(const float4*)(xrow + c*32 + quad*8);
    float4 v = *(const float4*)(xrow + c*32 + quad*8 + 4);
    float xv[8] = {u.x,u.y,u.z,u.w,v.x,v.y,v.z,v.w};
    #pragma unroll
    for (int j=0;j<8;++j) af[c][j] = (_Float16)(xv[j]*fi);
  }
  f4 acc[8];
  #pragma unroll
  for (int nt=0;nt<8;++nt) acc[nt] = (f4){0.f,0.f,0.f,0.f};
  const _Float16* Wc = Wrh + (size_t)ci*HH*HH;
  #pragma unroll
  for (int c=0;c<4;++c){
    #pragma unroll
    for (int nt=0;nt<8;++nt){
      int o = nt*16 + l15;
      h8 bh = *(const h8*)(Wc + (size_t)o*HH + c*32 + quad*8);
      acc[nt] = __builtin_amdgcn_mfma_f32_16x16x32_f16(af[c], bh, acc[nt], 0,0,0);
    }
  }
  float s1 = 0.f, s2 = 0.f;
  #pragma unroll
  for (int r=0;r<4;++r){
    int pD = base + 16*w + quad*4 + r;
    int e2 = -1, rk2 = 0;
    if (pD < cntc){ e2 = nodeList[ci*NN + pD]; rk2 = ranks[e2]; }
    if (e2 >= 0){
      const float* G = aggwl + ((size_t)ci*NCLS + rk2)*HH;
      float* drow = hcBuf + (size_t)e2*HH;
      #pragma unroll
      for (int nt=0;nt<8;++nt){
        int o = nt*16 + l15;
        float vv = acc[nt][r] + G[o];
        vv = vv>0.f ? vv : 0.f;
        drow[o] = vv;
        s1 += vv; s2 += vv*vv;
      }
    }
  }
  #pragma unroll
  for (int m=1;m<64;m<<=1){ s1 += __shfl_xor(s1,m); s2 += __shfl_xor(s2,m); }
  if (lane == 0){ rb[w] = s1; rb[4+w] = s2; }
  __syncthreads();
  if (t==0){
    atomicAdd(&sums[ci],    rb[0]+rb[1]+rb[2]+rb[3]);
    atomicAdd(&sums[16+ci], rb[4]+rb[5]+rb[6]+rb[7]);
  }
}

__global__ __launch_bounds__(256) void k_out(const float* __restrict__ hcBuf,
    const int* __restrict__ cols, const int* __restrict__ nodeCnt,
    const float* __restrict__ sums, float* __restrict__ out){
  int idx = blockIdx.x*256 + threadIdx.x;
  int e = idx >> 7;
  int ci = cols[e];
  float cntf = (float)nodeCnt[ci*16];
  float nel = fmaxf(cntf * (float)HH, 1.0f);
  float mu = sums[ci]/nel;
  float var = sums[16+ci]/nel - mu*mu;
  out[idx] = (hcBuf[idx]-mu)/sqrtf(var+EPSF);
}

extern "C" void kernel_launch(void* const* d_in, const int* in_sizes, int n_in,
                              void* d_out, int out_size, void* d_ws, size_t ws_size,
                              hipStream_t stream){
  const float* X    = (const float*)d_in[0];
  const float* W1   = (const float*)d_in[1];
  const float* b1   = (const float*)d_in[2];
  const float* ln_g = (const float*)d_in[3];
  const float* ln_b = (const float*)d_in[4];
  const float* W2   = (const float*)d_in[5];
  const float* b2   = (const float*)d_in[6];
  const float* Wl   = (const float*)d_in[7];
  const float* bl   = (const float*)d_in[8];
  const float* Wr   = (const float*)d_in[9];
  float* ws  = (float*)d_ws;
  float* outp = (float*)d_out;

  void* kargs[] = {
    (void*)&X, (void*)&W1, (void*)&b1, (void*)&ln_g, (void*)&ln_b,
    (void*)&W2, (void*)&b2, (void*)&Wl, (void*)&bl, (void*)&Wr,
    (void*)&ws, (void*)&outp
  };
  // 256 blocks = 1 block/CU: valid at any VGPR count (1 wave/SIMD needed).
  hipError_t err = hipLaunchCooperativeKernel((void*)k_all, dim3(256), dim3(256),
                                              kargs, 0, stream);
  if (err != hipSuccess){
    (void)hipGetLastError();  // clear sticky error
    err = hipLaunchCooperativeKernel((void*)k_all, dim3(128), dim3(256),
                                     kargs, 0, stream);
  }
  if (err != hipSuccess){
    (void)hipGetLastError();
    // Fallback: proven 10-kernel pipeline (R9).
    float* F      = ws + OFF_F;
    float* cnt    = ws + OFF_CNT;
    float* sums   = ws + OFF_SUMS;
    int*   nodeCnt= (int*)(ws + OFF_NCNT);
    float* logits = ws + OFF_LOGITS;
    int*   cols   = (int*)(ws + OFF_COLS);
    int*   ranks  = (int*)(ws + OFF_RANKS);
    float* fiSel  = ws + OFF_FISEL;
    int*   nodeList=(int*)(ws + OFF_NLIST);
    float* UP     = ws + OFF_UP;
    float* agg    = ws + OFF_AGG;
    float* hcBuf  = ws + OFF_HC;
    _Float16* hbase = (_Float16*)(ws + OFF_HALF);
    int cvtGrid = (ZERO_FLOATS > CVT_TOTAL ? ZERO_FLOATS : CVT_TOTAL + 255) / 256 + 1;
    k_cvt    <<<dim3(cvtGrid), dim3(256), 0, stream>>>(W1, Wl, Wr, hbase, ws);
    k_logits <<<dim3(NN*CCC/MT), dim3(256), 0, stream>>>(X, hbase+HOFF_W1H, hbase+HOFF_W1L,
                                                         b1, ln_g, ln_b, W2, b2, logits);
    k_topk   <<<dim3(NN/256), dim3(256), 0, stream>>>(logits, cols, ranks, fiSel, nodeCnt, nodeList);
    k_accF   <<<dim3(NN*KTOP/2), dim3(256), 0, stream>>>(X, cols, ranks, fiSel, F, cnt);
    k_pairs  <<<dim3(105,16), dim3(128), 0, stream>>>(F, UP);
    k_singles<<<dim3(15,16), dim3(128), 0, stream>>>(UP);
    k_as     <<<dim3(NCLS,16), dim3(128), 0, stream>>>(F, UP, cnt, agg);
    k_aggwl  <<<dim3((NCLS+MT-1)/MT,16), dim3(256), 0, stream>>>(agg, hbase+HOFF_WLH, bl);
    k_hc2    <<<dim3((NN/MT),16), dim3(256), 0, stream>>>(X, hbase+HOFF_WRH, ranks, fiSel,
                                                          nodeCnt, nodeList, agg, hcBuf, sums);
    k_out    <<<dim3(NN*KTOP*HH/256), dim3(256), 0, stream>>>(hcBuf, cols, nodeCnt, sums, outp);
  }
}

// Round 12
// 214.336 us; speedup vs baseline: 2.1936x; 2.1936x over previous
//
#include <hip/hip_runtime.h>
#include <hip/hip_bf16.h>

#define NN 3072
#define CCC 16
#define HH 128
#define KTOP 4
#define NCLS 455   // C(15,3)
#define NUP 120
#define EPSF 1e-5f

// ---------------- ws layout (float offsets) ----------------
#define OFF_F       0
#define SZ_F        (16*NCLS*HH)
#define OFF_CNT     (OFF_F + SZ_F)
#define SZ_CNT      (16*NCLS)
#define OFF_SUMS    (OFF_CNT + SZ_CNT)
#define SZ_SUMS     32
#define OFF_NCNT    (OFF_SUMS + SZ_SUMS)    // int nodeCnt[16*16] (64B-padded)
#define SZ_NCNT     256
#define ZERO_FLOATS (OFF_NCNT + SZ_NCNT)    // F, cnt, sums, nodeCnt zeroed by k_cvt
#define OFF_LOGITS  ZERO_FLOATS             // unused now (layout stability)
#define SZ_LOGITS   (NN*CCC)
#define OFF_COLS    (OFF_LOGITS + SZ_LOGITS)
#define SZ_E        (NN*KTOP)
#define OFF_RANKS   (OFF_COLS + SZ_E)
#define OFF_FISEL   (OFF_RANKS + SZ_E)
#define OFF_NLIST   (OFF_FISEL + SZ_E)
#define SZ_NLIST    (16*NN)
#define OFF_UP      (OFF_NLIST + SZ_NLIST)
#define SZ_UP       (16*NUP*HH)
#define OFF_AGG     (OFF_UP + SZ_UP)
#define OFF_HC      (OFF_AGG + SZ_F)
#define SZ_HC       (NN*KTOP*HH)
#define OFF_HALF    (OFF_HC + SZ_HC)
#define HOFF_W1H    0
#define HOFF_W1L    16384
#define HOFF_WLH    32768
#define HOFF_WRH    (32768 + 262144)
#define CVT_TOTAL   (16384 + 262144 + 262144)

#define MT 64

typedef _Float16 h8 __attribute__((ext_vector_type(8)));
typedef float    f4 __attribute__((ext_vector_type(4)));

__device__ __forceinline__ int C2i(int x){ return x*(x-1)/2; }
__device__ __forceinline__ int C3i(int x){ return x*(x-1)*(x-2)/6; }

__device__ __forceinline__ unsigned decode_mask(int r){
  int c = 2; while (c < 14 && C3i(c+1) <= r) c++;
  int rem = r - C3i(c);
  int b = 1; while (b < c-1 && C2i(b+1) <= rem) b++;
  int a = rem - C2i(b);
  return (1u<<a) | (1u<<b) | (1u<<c);
}

// ======== stage 0: zero accumulators + weight conversion to f16 ========
__global__ __launch_bounds__(256) void k_cvt(const float* __restrict__ W1,
    const float* __restrict__ Wl, const float* __restrict__ Wr,
    _Float16* __restrict__ hbase, float* __restrict__ ws){
  int i = blockIdx.x*256 + threadIdx.x;
  if (i < ZERO_FLOATS) ws[i] = 0.f;
  if (i < 16384){
    float x = W1[i];
    _Float16 h = (_Float16)x;
    hbase[HOFF_W1H + i] = h;
    hbase[HOFF_W1L + i] = (_Float16)(x - (float)h);
  }
  int j = i - 16384;
  if (j >= 0 && j < 262144) hbase[HOFF_WLH + j] = (_Float16)Wl[j];
  int k2 = i - (16384 + 262144);
  if (k2 >= 0 && k2 < 262144) hbase[HOFF_WRH + k2] = (_Float16)Wr[k2];
}

// ======== stage A (fused): logits GEMM + LN + top-4 + softmax + nodeList + F/cnt ========
// 768 blocks, 256 thr. Tile = 64 flat rows = 4 nodes x 16 channels; wave w owns node
// blockIdx*4+w. X rows are L2-hot for the F accumulation that follows.
__global__ __launch_bounds__(256) void k_fusedA(const float* __restrict__ X,
    const _Float16* __restrict__ W1h, const _Float16* __restrict__ W1l,
    const float* __restrict__ b1, const float* __restrict__ ln_g,
    const float* __restrict__ ln_b, const float* __restrict__ W2,
    const float* __restrict__ b2,
    int* __restrict__ cols, int* __restrict__ ranks, float* __restrict__ fiSel,
    int* __restrict__ nodeCnt, int* __restrict__ nodeList,
    float* __restrict__ F, float* __restrict__ cnt){
  int t = threadIdx.x;
  int w = t >> 6, lane = t & 63;
  int l15 = lane & 15, quad = lane >> 4;
  int base = blockIdx.x * MT;
  int mA = base + 16*w + l15;

  __shared__ float slog[4][16];
  __shared__ int   eCi[16], eRk[16], ePos[16];
  __shared__ float eFi[16];
  __shared__ int   lcnt[CCC], lbase[CCC];

  const float* xrow = X + (size_t)mA*HH;
  h8 ah[4], al[4];
  #pragma unroll
  for (int c=0;c<4;++c){
    float4 u = *(const float4*)(xrow + c*32 + quad*8);
    float4 v = *(const float4*)(xrow + c*32 + quad*8 + 4);
    float xv[8] = {u.x,u.y,u.z,u.w,v.x,v.y,v.z,v.w};
    #pragma unroll
    for (int j=0;j<8;++j){
      _Float16 hi = (_Float16)xv[j];
      ah[c][j] = hi;
      al[c][j] = (_Float16)(xv[j] - (float)hi);
    }
  }
  f4 acc[8];
  #pragma unroll
  for (int nt=0;nt<8;++nt) acc[nt] = (f4){0.f,0.f,0.f,0.f};
  #pragma unroll
  for (int c=0;c<4;++c){
    #pragma unroll
    for (int nt=0;nt<8;++nt){
      int o = nt*16 + l15;
      h8 bh  = *(const h8*)(W1h + (size_t)o*HH + c*32 + quad*8);
      h8 bl_ = *(const h8*)(W1l + (size_t)o*HH + c*32 + quad*8);
      acc[nt] = __builtin_amdgcn_mfma_f32_16x16x32_f16(ah[c], bh,  acc[nt], 0,0,0);
      acc[nt] = __builtin_amdgcn_mfma_f32_16x16x32_f16(al[c], bh,  acc[nt], 0,0,0);
      acc[nt] = __builtin_amdgcn_mfma_f32_16x16x32_f16(ah[c], bl_, acc[nt], 0,0,0);
      acc[nt] = __builtin_amdgcn_mfma_f32_16x16x32_f16(al[c], bl_, acc[nt], 0,0,0);
    }
  }
  float bv[8], gv[8], lv[8], wv[8];
  #pragma unroll
  for (int nt=0;nt<8;++nt){
    int o = nt*16 + l15;
    bv[nt]=b1[o]; gv[nt]=ln_g[o]; lv[nt]=ln_b[o]; wv[nt]=W2[o];
  }
  float b2v = b2[0];
  #pragma unroll
  for (int r=0;r<4;++r){
    float z[8];
    float s1=0.f, s2=0.f;
    #pragma unroll
    for (int nt=0;nt<8;++nt){
      float zz = acc[nt][r] + bv[nt];
      zz = zz>0.f ? zz : 0.f;
      z[nt] = zz; s1 += zz; s2 += zz*zz;
    }
    #pragma unroll
    for (int m=1;m<16;m<<=1){ s1 += __shfl_xor(s1,m); s2 += __shfl_xor(s2,m); }
    float mu = s1/(float)HH;
    float var = s2/(float)HH - mu*mu;
    float rs = 1.0f/sqrtf(var+EPSF);
    float s3 = 0.f;
    #pragma unroll
    for (int nt=0;nt<8;++nt){
      float zn = (z[nt]-mu)*rs*gv[nt] + lv[nt];
      s3 += zn*wv[nt];
    }
    #pragma unroll
    for (int m=1;m<16;m<<=1) s3 += __shfl_xor(s3,m);
    if (l15 == 0) slog[w][quad*4 + r] = s3 + b2v;   // node blockIdx*4+w, channel quad*4+r
  }
  if (t < CCC) lcnt[t] = 0;
  __syncthreads();

  // per-node top-4 + softmax (threads 0..3 each own one node)
  if (t < 4){
    float l[CCC];
    #pragma unroll
    for (int c=0;c<CCC;++c) l[c] = slog[t][c];
    unsigned mask = 0;
    #pragma unroll
    for (int k=0;k<KTOP;++k){
      float best = -3e38f; int bi = 0;
      #pragma unroll
      for (int c=0;c<CCC;++c){
        bool taken = (mask>>c)&1u;
        if (!taken && l[c] > best){ best = l[c]; bi = c; }
      }
      mask |= 1u<<bi;
    }
    float m = -3e38f;
    #pragma unroll
    for (int c=0;c<CCC;++c) m = l[c]>m ? l[c] : m;
    float s = 0.f;
    #pragma unroll
    for (int c=0;c<CCC;++c) s += expf(l[c]-m);
    float inv = 1.0f/s;
    int n = blockIdx.x*4 + t;
    unsigned m2 = mask;
    for (int j=0;j<KTOP;++j){
      int ci = __ffs(m2)-1; m2 &= m2-1u;
      unsigned rest = mask & ~(1u<<ci);
      int v[3]; unsigned r2 = rest;
      #pragma unroll
      for (int q=0;q<3;++q){ int col = __ffs(r2)-1; r2 &= r2-1u; v[q] = col - (col>ci ? 1:0); }
      int rank = C3i(v[2]) + C2i(v[1]) + v[0];
      int e4 = n*KTOP + j;
      float fi = expf(l[ci]-m)*inv;
      cols[e4] = ci; ranks[e4] = rank; fiSel[e4] = fi;
      int slot = t*KTOP + j;
      eCi[slot] = ci; eRk[slot] = rank; eFi[slot] = fi;
      ePos[slot] = atomicAdd(&lcnt[ci], 1);
      atomicAdd(&cnt[ci*NCLS + rank], 1.0f);
    }
  }
  __syncthreads();
  if (t < CCC && lcnt[t] > 0) lbase[t] = atomicAdd(&nodeCnt[t*16], lcnt[t]);
  __syncthreads();
  if (t < 16){
    int ci = eCi[t];
    int n = blockIdx.x*4 + (t>>2);
    nodeList[ci*NN + lbase[ci] + ePos[t]] = n*KTOP + (t&3);
  }
  __syncthreads();
  // F accumulation: 16 selections x 128 cols, X rows L2-hot from the GEMM above
  for (int idx = t; idx < 16*HH; idx += 256){
    int slot = idx >> 7, col = idx & 127;
    int ci = eCi[slot], rank = eRk[slot];
    float fi = eFi[slot];
    int n = blockIdx.x*4 + (slot>>2);
    float v = X[((size_t)n*CCC + ci)*HH + col] * fi;
    atomicAdd(&F[((size_t)ci*NCLS + rank)*HH + col], v);
  }
}

// ======== stage B (merged): pairs P_xy (13 summands) + singles U_x (91 direct) ========
__global__ __launch_bounds__(128) void k_puB(const float* __restrict__ F, float* __restrict__ UP){
  int t = threadIdx.x;
  int u = blockIdx.x, ci = blockIdx.y;
  const float* Fc = F + (size_t)ci*NCLS*HH;
  float acc = 0.f;
  if (u < 105){
    int p = u;
    int pb = 1; while (pb < 14 && C2i(pb+1) <= p) pb++;
    int pa = p - C2i(pb);
    #pragma unroll
    for (int z = 0; z < 15; ++z){
      if (z == pa || z == pb) continue;
      int lo, mid, hi;
      if (z < pa){ lo = z;  mid = pa; hi = pb; }
      else if (z < pb){ lo = pa; mid = z;  hi = pb; }
      else { lo = pa; mid = pb; hi = z; }
      acc += Fc[(size_t)(C3i(hi)+C2i(mid)+lo)*HH + t];
    }
    UP[((size_t)ci*NUP + 15 + p)*HH + t] = acc;
  } else {
    int x = u - 105;
    // U_x = sum over all 91 triples containing x (each triple counted once)
    #pragma unroll
    for (int y = 0; y < 15; ++y){
      if (y == x) continue;
      for (int z = y+1; z < 15; ++z){
        if (z == x) continue;
        int lo, mid, hi;
        if (x < y){ lo = x; mid = y; hi = z; }
        else if (x < z){ lo = y; mid = x; hi = z; }
        else { lo = y; mid = z; hi = x; }
        acc += Fc[(size_t)(C3i(hi)+C2i(mid)+lo)*HH + t];
      }
    }
    UP[((size_t)ci*NUP + x)*HH + t] = acc;
  }
}

// ======== stage D2: per-class agg via inclusion-exclusion (+deg fused) ========
__global__ __launch_bounds__(128) void k_as(const float* __restrict__ F,
    const float* __restrict__ UP, const float* __restrict__ cnt, float* __restrict__ agg){
  __shared__ unsigned tm[NCLS];
  __shared__ float dred[2];
  int t = threadIdx.x;
  for (int i=t;i<NCLS;i+=128) tm[i] = decode_mask(i);
  __syncthreads();
  int r = blockIdx.x, ci = blockIdx.y;
  unsigned m = tm[r];
  float d = 0.f;
  const float* cc = cnt + ci*NCLS;
  for (int tp=t; tp<NCLS; tp+=128)
    if (m & tm[tp]) d += cc[tp];
  #pragma unroll
  for (int mm=1; mm<64; mm<<=1) d += __shfl_xor(d, mm);
  if ((t&63)==0) dred[t>>6] = d;
  __syncthreads();
  float invd = 1.0f / fmaxf(dred[0]+dred[1], 1.0f);
  int c = 2; while (c < 14 && C3i(c+1) <= r) c++;
  int rem = r - C3i(c);
  int b = 1; while (b < c-1 && C2i(b+1) <= rem) b++;
  int a = rem - C2i(b);
  const float* U = UP + ci*NUP*HH;
  int pab = 15 + C2i(b) + a;
  int pac = 15 + C2i(c) + a;
  int pbc = 15 + C2i(c) + b;
  float v = U[a*HH+t] + U[b*HH+t] + U[c*HH+t]
          - U[pab*HH+t] - U[pac*HH+t] - U[pbc*HH+t]
          + F[(ci*NCLS+r)*HH + t];
  agg[(ci*NCLS+r)*HH + t] = v * invd;
}

// ======== stage E1: AggWl = Agg @ Wl^T + bl (per class, in-place, f16 MFMA) ========
__global__ __launch_bounds__(256) void k_aggwl(float* __restrict__ agg,
    const _Float16* __restrict__ Wlh, const float* __restrict__ bl){
  int t = threadIdx.x;
  int w = t >> 6;
  int lane = t & 63;
  int l15 = lane & 15, quad = lane >> 4;
  int ci = blockIdx.y;
  int base = blockIdx.x * MT;
  int rowA = base + 16*w + l15; if (rowA > NCLS-1) rowA = NCLS-1;
  const float* arow = agg + ((size_t)ci*NCLS + rowA)*HH;
  h8 af[4];
  #pragma unroll
  for (int c=0;c<4;++c){
    float4 u = *(const float4*)(arow + c*32 + quad*8);
    float4 v = *(const float4*)(arow + c*32 + quad*8 + 4);
    float xv[8] = {u.x,u.y,u.z,u.w,v.x,v.y,v.z,v.w};
    #pragma unroll
    for (int j=0;j<8;++j) af[c][j] = (_Float16)xv[j];
  }
  f4 acc[8];
  #pragma unroll
  for (int nt=0;nt<8;++nt) acc[nt] = (f4){0.f,0.f,0.f,0.f};
  const _Float16* Wc = Wlh + (size_t)ci*HH*HH;
  #pragma unroll
  for (int c=0;c<4;++c){
    #pragma unroll
    for (int nt=0;nt<8;++nt){
      int o = nt*16 + l15;
      h8 bh = *(const h8*)(Wc + (size_t)o*HH + c*32 + quad*8);
      acc[nt] = __builtin_amdgcn_mfma_f32_16x16x32_f16(af[c], bh, acc[nt], 0,0,0);
    }
  }
  #pragma unroll
  for (int r=0;r<4;++r){
    int row2 = base + 16*w + quad*4 + r;
    if (row2 < NCLS){
      float* drow = agg + ((size_t)ci*NCLS + row2)*HH;
      #pragma unroll
      for (int nt=0;nt<8;++nt){
        int o = nt*16 + l15;
        drow[o] = acc[nt][r] + bl[ci*HH + o];
      }
    }
  }
}

// ======== stage E2: hc = relu(AggWl[class] + fi*X @ Wr^T) (f16 MFMA) ========
__global__ __launch_bounds__(256) void k_hc2(const float* __restrict__ X,
    const _Float16* __restrict__ Wrh,
    const int* __restrict__ ranks, const float* __restrict__ fiSel,
    const int* __restrict__ nodeCnt, const int* __restrict__ nodeList,
    const float* __restrict__ aggwl, float* __restrict__ hcBuf, float* __restrict__ sums){
  int ci = blockIdx.y;
  int cntc = nodeCnt[ci*16];
  int base = blockIdx.x * MT;
  if (base >= cntc) return;
  __shared__ float rb[8];
  int t = threadIdx.x;
  int w = t >> 6;
  int lane = t & 63;
  int l15 = lane & 15, quad = lane >> 4;
  int pA = base + 16*w + l15;
  float fi = 0.f; int nA = 0;
  if (pA < cntc){
    int e = nodeList[ci*NN + pA];
    fi = fiSel[e]; nA = e >> 2;
  }
  const float* xrow = X + ((size_t)nA*CCC + ci)*HH;
  h8 af[4];
  #pragma unroll
  for (int c=0;c<4;++c){
    float4 u = *(const float4*)(xrow + c*32 + quad*8);
    float4 v = *(const float4*)(xrow + c*32 + quad*8 + 4);
    float xv[8] = {u.x,u.y,u.z,u.w,v.x,v.y,v.z,v.w};
    #pragma unroll
    for (int j=0;j<8;++j) af[c][j] = (_Float16)(xv[j]*fi);
  }
  f4 acc[8];
  #pragma unroll
  for (int nt=0;nt<8;++nt) acc[nt] = (f4){0.f,0.f,0.f,0.f};
  const _Float16* Wc = Wrh + (size_t)ci*HH*HH;
  #pragma unroll
  for (int c=0;c<4;++c){
    #pragma unroll
    for (int nt=0;nt<8;++nt){
      int o = nt*16 + l15;
      h8 bh = *(const h8*)(Wc + (size_t)o*HH + c*32 + quad*8);
      acc[nt] = __builtin_amdgcn_mfma_f32_16x16x32_f16(af[c], bh, acc[nt], 0,0,0);
    }
  }
  float s1 = 0.f, s2 = 0.f;
  #pragma unroll
  for (int r=0;r<4;++r){
    int pD = base + 16*w + quad*4 + r;
    int e2 = -1, rk2 = 0;
    if (pD < cntc){ e2 = nodeList[ci*NN + pD]; rk2 = ranks[e2]; }
    if (e2 >= 0){
      const float* G = aggwl + ((size_t)ci*NCLS + rk2)*HH;
      float* drow = hcBuf + (size_t)e2*HH;
      #pragma unroll
      for (int nt=0;nt<8;++nt){
        int o = nt*16 + l15;
        float vv = acc[nt][r] + G[o];
        vv = vv>0.f ? vv : 0.f;
        drow[o] = vv;
        s1 += vv; s2 += vv*vv;
      }
    }
  }
  #pragma unroll
  for (int m=1;m<64;m<<=1){ s1 += __shfl_xor(s1,m); s2 += __shfl_xor(s2,m); }
  if (lane == 0){ rb[w] = s1; rb[4+w] = s2; }
  __syncthreads();
  if (t==0){
    atomicAdd(&sums[ci],    rb[0]+rb[1]+rb[2]+rb[3]);
    atomicAdd(&sums[16+ci], rb[4]+rb[5]+rb[6]+rb[7]);
  }
}

// ======== stage F: masked mean/var normalize, write output ========
__global__ __launch_bounds__(256) void k_out(const float* __restrict__ hcBuf,
    const int* __restrict__ cols, const int* __restrict__ nodeCnt,
    const float* __restrict__ sums, float* __restrict__ out){
  int idx = blockIdx.x*256 + threadIdx.x;
  int e = idx >> 7;
  int ci = cols[e];
  float cntf = (float)nodeCnt[ci*16];
  float nel = fmaxf(cntf * (float)HH, 1.0f);
  float mu = sums[ci]/nel;
  float var = sums[16+ci]/nel - mu*mu;
  out[idx] = (hcBuf[idx]-mu)/sqrtf(var+EPSF);
}

extern "C" void kernel_launch(void* const* d_in, const int* in_sizes, int n_in,
                              void* d_out, int out_size, void* d_ws, size_t ws_size,
                              hipStream_t stream){
  const float* X    = (const float*)d_in[0];
  const float* W1   = (const float*)d_in[1];
  const float* b1   = (const float*)d_in[2];
  const float* ln_g = (const float*)d_in[3];
  const float* ln_b = (const float*)d_in[4];
  const float* W2   = (const float*)d_in[5];
  const float* b2   = (const float*)d_in[6];
  const float* Wl   = (const float*)d_in[7];
  const float* bl   = (const float*)d_in[8];
  const float* Wr   = (const float*)d_in[9];
  float* ws = (float*)d_ws;
  float* F      = ws + OFF_F;
  float* cnt    = ws + OFF_CNT;
  float* sums   = ws + OFF_SUMS;
  int*   nodeCnt= (int*)(ws + OFF_NCNT);
  int*   cols   = (int*)(ws + OFF_COLS);
  int*   ranks  = (int*)(ws + OFF_RANKS);
  float* fiSel  = ws + OFF_FISEL;
  int*   nodeList=(int*)(ws + OFF_NLIST);
  float* UP     = ws + OFF_UP;
  float* agg    = ws + OFF_AGG;
  float* hcBuf  = ws + OFF_HC;
  _Float16* hbase = (_Float16*)(ws + OFF_HALF);
  float* out    = (float*)d_out;

  int cvtGrid = (ZERO_FLOATS > CVT_TOTAL ? ZERO_FLOATS : CVT_TOTAL + 255) / 256 + 1;
  k_cvt    <<<dim3(cvtGrid), dim3(256), 0, stream>>>(W1, Wl, Wr, hbase, ws);
  k_fusedA <<<dim3(NN*CCC/MT), dim3(256), 0, stream>>>(X, hbase+HOFF_W1H, hbase+HOFF_W1L,
                                                       b1, ln_g, ln_b, W2, b2,
                                                       cols, ranks, fiSel, nodeCnt, nodeList,
                                                       F, cnt);
  k_puB    <<<dim3(NUP,16), dim3(128), 0, stream>>>(F, UP);
  k_as     <<<dim3(NCLS,16), dim3(128), 0, stream>>>(F, UP, cnt, agg);
  k_aggwl  <<<dim3((NCLS+MT-1)/MT,16), dim3(256), 0, stream>>>(agg, hbase+HOFF_WLH, bl);
  k_hc2    <<<dim3((NN/MT),16), dim3(256), 0, stream>>>(X, hbase+HOFF_WRH, ranks, fiSel,
                                                        nodeCnt, nodeList, agg, hcBuf, sums);
  k_out    <<<dim3(NN*KTOP*HH/256), dim3(256), 0, stream>>>(hcBuf, cols, nodeCnt, sums, out);
}

// Round 13
// 195.850 us; speedup vs baseline: 2.4007x; 1.0944x over previous
//
#include <hip/hip_runtime.h>
#include <hip/hip_bf16.h>

#define NN 3072
#define CCC 16
#define HH 128
#define KTOP 4
#define NCLS 455   // C(15,3)
#define NUP 120
#define EPSF 1e-5f

// ---------------- ws layout (float offsets) ----------------
#define OFF_F       0
#define SZ_F        (16*NCLS*HH)
#define OFF_CNT     (OFF_F + SZ_F)
#define SZ_CNT      (16*NCLS)
#define OFF_SUMS    (OFF_CNT + SZ_CNT)
#define SZ_SUMS     32
#define OFF_NCNT    (OFF_SUMS + SZ_SUMS)    // int nodeCnt[16*16] (64B-padded)
#define SZ_NCNT     256
#define ZERO_FLOATS (OFF_NCNT + SZ_NCNT)    // F, cnt, sums, nodeCnt zeroed by k_cvt
#define OFF_LOGITS  ZERO_FLOATS             // unused (layout stability)
#define SZ_LOGITS   (NN*CCC)
#define OFF_COLS    (OFF_LOGITS + SZ_LOGITS)
#define SZ_E        (NN*KTOP)
#define OFF_RANKS   (OFF_COLS + SZ_E)
#define OFF_FISEL   (OFF_RANKS + SZ_E)
#define OFF_NLIST   (OFF_FISEL + SZ_E)
#define SZ_NLIST    (16*NN)
#define OFF_UP      (OFF_NLIST + SZ_NLIST)
#define SZ_UP       (16*NUP*HH)
#define OFF_AGG     (OFF_UP + SZ_UP)
#define OFF_HC      (OFF_AGG + SZ_F)
#define SZ_HC       (NN*KTOP*HH)
#define OFF_HALF    (OFF_HC + SZ_HC)
#define HOFF_W1H    0
#define HOFF_W1L    16384
#define HOFF_WLH    32768
#define HOFF_WRH    (32768 + 262144)
#define CVT_TOTAL   (16384 + 262144 + 262144)

#define MT 64

typedef _Float16 h8 __attribute__((ext_vector_type(8)));
typedef float    f4 __attribute__((ext_vector_type(4)));

__device__ __forceinline__ int C2i(int x){ return x*(x-1)/2; }
__device__ __forceinline__ int C3i(int x){ return x*(x-1)*(x-2)/6; }

__device__ __forceinline__ unsigned decode_mask(int r){
  int c = 2; while (c < 14 && C3i(c+1) <= r) c++;
  int rem = r - C3i(c);
  int b = 1; while (b < c-1 && C2i(b+1) <= rem) b++;
  int a = rem - C2i(b);
  return (1u<<a) | (1u<<b) | (1u<<c);
}

// ======== stage 0: zero accumulators + weight conversion to f16 ========
__global__ __launch_bounds__(256) void k_cvt(const float* __restrict__ W1,
    const float* __restrict__ Wl, const float* __restrict__ Wr,
    _Float16* __restrict__ hbase, float* __restrict__ ws){
  int i = blockIdx.x*256 + threadIdx.x;
  if (i < ZERO_FLOATS) ws[i] = 0.f;
  if (i < 16384){
    float x = W1[i];
    _Float16 h = (_Float16)x;
    hbase[HOFF_W1H + i] = h;
    hbase[HOFF_W1L + i] = (_Float16)(x - (float)h);
  }
  int j = i - 16384;
  if (j >= 0 && j < 262144) hbase[HOFF_WLH + j] = (_Float16)Wl[j];
  int k2 = i - (16384 + 262144);
  if (k2 >= 0 && k2 < 262144) hbase[HOFF_WRH + k2] = (_Float16)Wr[k2];
}

// ======== stage A (fused): logits GEMM + LN + top-4 + softmax + nodeList + F/cnt ========
// 768 blocks, 256 thr. Tile = 64 flat rows = 4 nodes x 16 channels; wave w owns node
// blockIdx*4+w. X rows stay L2-hot for the F accumulation tail.
__global__ __launch_bounds__(256) void k_fusedA(const float* __restrict__ X,
    const _Float16* __restrict__ W1h, const _Float16* __restrict__ W1l,
    const float* __restrict__ b1, const float* __restrict__ ln_g,
    const float* __restrict__ ln_b, const float* __restrict__ W2,
    const float* __restrict__ b2,
    int* __restrict__ cols, int* __restrict__ ranks, float* __restrict__ fiSel,
    int* __restrict__ nodeCnt, int* __restrict__ nodeList,
    float* __restrict__ F, float* __restrict__ cnt){
  int t = threadIdx.x;
  int w = t >> 6, lane = t & 63;
  int l15 = lane & 15, quad = lane >> 4;
  int base = blockIdx.x * MT;
  int mA = base + 16*w + l15;

  __shared__ float slog[4][16];
  __shared__ int   eCi[16], eRk[16], ePos[16];
  __shared__ float eFi[16];
  __shared__ int   lcnt[CCC], lbase[CCC];

  const float* xrow = X + (size_t)mA*HH;
  h8 ah[4], al[4];
  #pragma unroll
  for (int c=0;c<4;++c){
    float4 u = *(const float4*)(xrow + c*32 + quad*8);
    float4 v = *(const float4*)(xrow + c*32 + quad*8 + 4);
    float xv[8] = {u.x,u.y,u.z,u.w,v.x,v.y,v.z,v.w};
    #pragma unroll
    for (int j=0;j<8;++j){
      _Float16 hi = (_Float16)xv[j];
      ah[c][j] = hi;
      al[c][j] = (_Float16)(xv[j] - (float)hi);
    }
  }
  f4 acc[8];
  #pragma unroll
  for (int nt=0;nt<8;++nt) acc[nt] = (f4){0.f,0.f,0.f,0.f};
  #pragma unroll
  for (int c=0;c<4;++c){
    #pragma unroll
    for (int nt=0;nt<8;++nt){
      int o = nt*16 + l15;
      h8 bh  = *(const h8*)(W1h + (size_t)o*HH + c*32 + quad*8);
      h8 bl_ = *(const h8*)(W1l + (size_t)o*HH + c*32 + quad*8);
      acc[nt] = __builtin_amdgcn_mfma_f32_16x16x32_f16(ah[c], bh,  acc[nt], 0,0,0);
      acc[nt] = __builtin_amdgcn_mfma_f32_16x16x32_f16(al[c], bh,  acc[nt], 0,0,0);
      acc[nt] = __builtin_amdgcn_mfma_f32_16x16x32_f16(ah[c], bl_, acc[nt], 0,0,0);
    }
  }
  float bv[8], gv[8], lv[8], wv[8];
  #pragma unroll
  for (int nt=0;nt<8;++nt){
    int o = nt*16 + l15;
    bv[nt]=b1[o]; gv[nt]=ln_g[o]; lv[nt]=ln_b[o]; wv[nt]=W2[o];
  }
  float b2v = b2[0];
  #pragma unroll
  for (int r=0;r<4;++r){
    float z[8];
    float s1=0.f, s2=0.f;
    #pragma unroll
    for (int nt=0;nt<8;++nt){
      float zz = acc[nt][r] + bv[nt];
      zz = zz>0.f ? zz : 0.f;
      z[nt] = zz; s1 += zz; s2 += zz*zz;
    }
    #pragma unroll
    for (int m=1;m<16;m<<=1){ s1 += __shfl_xor(s1,m); s2 += __shfl_xor(s2,m); }
    float mu = s1/(float)HH;
    float var = s2/(float)HH - mu*mu;
    float rs = 1.0f/sqrtf(var+EPSF);
    float s3 = 0.f;
    #pragma unroll
    for (int nt=0;nt<8;++nt){
      float zn = (z[nt]-mu)*rs*gv[nt] + lv[nt];
      s3 += zn*wv[nt];
    }
    #pragma unroll
    for (int m=1;m<16;m<<=1) s3 += __shfl_xor(s3,m);
    if (l15 == 0) slog[w][quad*4 + r] = s3 + b2v;
  }
  if (t < CCC) lcnt[t] = 0;
  __syncthreads();

  if (t < 4){
    float l[CCC];
    #pragma unroll
    for (int c=0;c<CCC;++c) l[c] = slog[t][c];
    unsigned mask = 0;
    #pragma unroll
    for (int k=0;k<KTOP;++k){
      float best = -3e38f; int bi = 0;
      #pragma unroll
      for (int c=0;c<CCC;++c){
        bool taken = (mask>>c)&1u;
        if (!taken && l[c] > best){ best = l[c]; bi = c; }
      }
      mask |= 1u<<bi;
    }
    float m = -3e38f;
    #pragma unroll
    for (int c=0;c<CCC;++c) m = l[c]>m ? l[c] : m;
    float s = 0.f;
    #pragma unroll
    for (int c=0;c<CCC;++c) s += expf(l[c]-m);
    float inv = 1.0f/s;
    int n = blockIdx.x*4 + t;
    unsigned m2 = mask;
    for (int j=0;j<KTOP;++j){
      int ci = __ffs(m2)-1; m2 &= m2-1u;
      unsigned rest = mask & ~(1u<<ci);
      int v[3]; unsigned r2 = rest;
      #pragma unroll
      for (int q=0;q<3;++q){ int col = __ffs(r2)-1; r2 &= r2-1u; v[q] = col - (col>ci ? 1:0); }
      int rank = C3i(v[2]) + C2i(v[1]) + v[0];
      int e4 = n*KTOP + j;
      float fi = expf(l[ci]-m)*inv;
      cols[e4] = ci; ranks[e4] = rank; fiSel[e4] = fi;
      int slot = t*KTOP + j;
      eCi[slot] = ci; eRk[slot] = rank; eFi[slot] = fi;
      ePos[slot] = atomicAdd(&lcnt[ci], 1);
      atomicAdd(&cnt[ci*NCLS + rank], 1.0f);
    }
  }
  __syncthreads();
  if (t < CCC && lcnt[t] > 0) lbase[t] = atomicAdd(&nodeCnt[t*16], lcnt[t]);
  __syncthreads();
  if (t < 16){
    int ci = eCi[t];
    int n = blockIdx.x*4 + (t>>2);
    nodeList[ci*NN + lbase[ci] + ePos[t]] = n*KTOP + (t&3);
  }
  __syncthreads();
  for (int idx = t; idx < 16*HH; idx += 256){
    int slot = idx >> 7, col = idx & 127;
    int ci = eCi[slot], rank = eRk[slot];
    float fi = eFi[slot];
    int n = blockIdx.x*4 + (slot>>2);
    float v = X[((size_t)n*CCC + ci)*HH + col] * fi;
    atomicAdd(&F[((size_t)ci*NCLS + rank)*HH + col], v);
  }
}

// ======== stage D1a: pairs P_xy = sum_z F[{x,y,z}] (13 unrolled summands) ========
__global__ __launch_bounds__(128) void k_pairs(const float* __restrict__ F, float* __restrict__ UP){
  int t = threadIdx.x;
  int p = blockIdx.x, ci = blockIdx.y;
  int pb = 1; while (pb < 14 && C2i(pb+1) <= p) pb++;
  int pa = p - C2i(pb);
  const float* Fc = F + (size_t)ci*NCLS*HH;
  float acc = 0.f;
  #pragma unroll
  for (int z = 0; z < 15; ++z){
    if (z == pa || z == pb) continue;
    int lo, mid, hi;
    if (z < pa){ lo = z;  mid = pa; hi = pb; }
    else if (z < pb){ lo = pa; mid = z;  hi = pb; }
    else { lo = pa; mid = pb; hi = z; }
    int rank = C3i(hi) + C2i(mid) + lo;
    acc += Fc[(size_t)rank*HH + t];
  }
  UP[((size_t)ci*NUP + 15 + p)*HH + t] = acc;
}

// ======== stage D1b: singles U_x = 0.5 * sum_{y!=x} P_xy (14 unrolled) ========
__global__ __launch_bounds__(128) void k_singles(float* __restrict__ UP){
  int t = threadIdx.x;
  int x = blockIdx.x, ci = blockIdx.y;
  const float* Pc = UP + ((size_t)ci*NUP + 15)*HH;
  float acc = 0.f;
  #pragma unroll
  for (int y = 0; y < 15; ++y){
    if (y == x) continue;
    int lo = x < y ? x : y, hi = x < y ? y : x;
    int pi = C2i(hi) + lo;
    acc += Pc[(size_t)pi*HH + t];
  }
  UP[((size_t)ci*NUP + x)*HH + t] = 0.5f*acc;
}

// ======== stage D2: per-class agg via inclusion-exclusion (+deg fused) ========
__global__ __launch_bounds__(128) void k_as(const float* __restrict__ F,
    const float* __restrict__ UP, const float* __restrict__ cnt, float* __restrict__ agg){
  __shared__ unsigned tm[NCLS];
  __shared__ float dred[2];
  int t = threadIdx.x;
  for (int i=t;i<NCLS;i+=128) tm[i] = decode_mask(i);
  __syncthreads();
  int r = blockIdx.x, ci = blockIdx.y;
  unsigned m = tm[r];
  float d = 0.f;
  const float* cc = cnt + ci*NCLS;
  for (int tp=t; tp<NCLS; tp+=128)
    if (m & tm[tp]) d += cc[tp];
  #pragma unroll
  for (int mm=1; mm<64; mm<<=1) d += __shfl_xor(d, mm);
  if ((t&63)==0) dred[t>>6] = d;
  __syncthreads();
  float invd = 1.0f / fmaxf(dred[0]+dred[1], 1.0f);
  int c = 2; while (c < 14 && C3i(c+1) <= r) c++;
  int rem = r - C3i(c);
  int b = 1; while (b < c-1 && C2i(b+1) <= rem) b++;
  int a = rem - C2i(b);
  const float* U = UP + ci*NUP*HH;
  int pab = 15 + C2i(b) + a;
  int pac = 15 + C2i(c) + a;
  int pbc = 15 + C2i(c) + b;
  float v = U[a*HH+t] + U[b*HH+t] + U[c*HH+t]
          - U[pab*HH+t] - U[pac*HH+t] - U[pbc*HH+t]
          + F[(ci*NCLS+r)*HH + t];
  agg[(ci*NCLS+r)*HH + t] = v * invd;
}

// ======== stage E1: AggWl = Agg @ Wl^T + bl (per class, in-place, f16 MFMA) ========
__global__ __launch_bounds__(256) void k_aggwl(float* __restrict__ agg,
    const _Float16* __restrict__ Wlh, const float* __restrict__ bl){
  int t = threadIdx.x;
  int w = t >> 6;
  int lane = t & 63;
  int l15 = lane & 15, quad = lane >> 4;
  int ci = blockIdx.y;
  int base = blockIdx.x * MT;
  int rowA = base + 16*w + l15; if (rowA > NCLS-1) rowA = NCLS-1;
  const float* arow = agg + ((size_t)ci*NCLS + rowA)*HH;
  h8 af[4];
  #pragma unroll
  for (int c=0;c<4;++c){
    float4 u = *(const float4*)(arow + c*32 + quad*8);
    float4 v = *(const float4*)(arow + c*32 + quad*8 + 4);
    float xv[8] = {u.x,u.y,u.z,u.w,v.x,v.y,v.z,v.w};
    #pragma unroll
    for (int j=0;j<8;++j) af[c][j] = (_Float16)xv[j];
  }
  f4 acc[8];
  #pragma unroll
  for (int nt=0;nt<8;++nt) acc[nt] = (f4){0.f,0.f,0.f,0.f};
  const _Float16* Wc = Wlh + (size_t)ci*HH*HH;
  #pragma unroll
  for (int c=0;c<4;++c){
    #pragma unroll
    for (int nt=0;nt<8;++nt){
      int o = nt*16 + l15;
      h8 bh = *(const h8*)(Wc + (size_t)o*HH + c*32 + quad*8);
      acc[nt] = __builtin_amdgcn_mfma_f32_16x16x32_f16(af[c], bh, acc[nt], 0,0,0);
    }
  }
  #pragma unroll
  for (int r=0;r<4;++r){
    int row2 = base + 16*w + quad*4 + r;
    if (row2 < NCLS){
      float* drow = agg + ((size_t)ci*NCLS + row2)*HH;
      #pragma unroll
      for (int nt=0;nt<8;++nt){
        int o = nt*16 + l15;
        drow[o] = acc[nt][r] + bl[ci*HH + o];
      }
    }
  }
}

// ======== stage E2: hc = relu(AggWl[class] + fi*X @ Wr^T) (f16 MFMA) ========
__global__ __launch_bounds__(256) void k_hc2(const float* __restrict__ X,
    const _Float16* __restrict__ Wrh,
    const int* __restrict__ ranks, const float* __restrict__ fiSel,
    const int* __restrict__ nodeCnt, const int* __restrict__ nodeList,
    const float* __restrict__ aggwl, float* __restrict__ hcBuf, float* __restrict__ sums){
  int ci = blockIdx.y;
  int cntc = nodeCnt[ci*16];
  int base = blockIdx.x * MT;
  if (base >= cntc) return;
  __shared__ float rb[8];
  int t = threadIdx.x;
  int w = t >> 6;
  int lane = t & 63;
  int l15 = lane & 15, quad = lane >> 4;
  int pA = base + 16*w + l15;
  float fi = 0.f; int nA = 0;
  if (pA < cntc){
    int e = nodeList[ci*NN + pA];
    fi = fiSel[e]; nA = e >> 2;
  }
  const float* xrow = X + ((size_t)nA*CCC + ci)*HH;
  h8 af[4];
  #pragma unroll
  for (int c=0;c<4;++c){
    float4 u = *(const float4*)(xrow + c*32 + quad*8);
    float4 v = *(const float4*)(xrow + c*32 + quad*8 + 4);
    float xv[8] = {u.x,u.y,u.z,u.w,v.x,v.y,v.z,v.w};
    #pragma unroll
    for (int j=0;j<8;++j) af[c][j] = (_Float16)(xv[j]*fi);
  }
  f4 acc[8];
  #pragma unroll
  for (int nt=0;nt<8;++nt) acc[nt] = (f4){0.f,0.f,0.f,0.f};
  const _Float16* Wc = Wrh + (size_t)ci*HH*HH;
  #pragma unroll
  for (int c=0;c<4;++c){
    #pragma unroll
    for (int nt=0;nt<8;++nt){
      int o = nt*16 + l15;
      h8 bh = *(const h8*)(Wc + (size_t)o*HH + c*32 + quad*8);
      acc[nt] = __builtin_amdgcn_mfma_f32_16x16x32_f16(af[c], bh, acc[nt], 0,0,0);
    }
  }
  float s1 = 0.f, s2 = 0.f;
  #pragma unroll
  for (int r=0;r<4;++r){
    int pD = base + 16*w + quad*4 + r;
    int e2 = -1, rk2 = 0;
    if (pD < cntc){ e2 = nodeList[ci*NN + pD]; rk2 = ranks[e2]; }
    if (e2 >= 0){
      const float* G = aggwl + ((size_t)ci*NCLS + rk2)*HH;
      float* drow = hcBuf + (size_t)e2*HH;
      #pragma unroll
      for (int nt=0;nt<8;++nt){
        int o = nt*16 + l15;
        float vv = acc[nt][r] + G[o];
        vv = vv>0.f ? vv : 0.f;
        drow[o] = vv;
        s1 += vv; s2 += vv*vv;
      }
    }
  }
  #pragma unroll
  for (int m=1;m<64;m<<=1){ s1 += __shfl_xor(s1,m); s2 += __shfl_xor(s2,m); }
  if (lane == 0){ rb[w] = s1; rb[4+w] = s2; }
  __syncthreads();
  if (t==0){
    atomicAdd(&sums[ci],    rb[0]+rb[1]+rb[2]+rb[3]);
    atomicAdd(&sums[16+ci], rb[4]+rb[5]+rb[6]+rb[7]);
  }
}

// ======== stage F: masked mean/var normalize, write output (float4) ========
__global__ __launch_bounds__(256) void k_out(const float* __restrict__ hcBuf,
    const int* __restrict__ cols, const int* __restrict__ nodeCnt,
    const float* __restrict__ sums, float* __restrict__ out){
  int idx4 = (blockIdx.x*256 + threadIdx.x) << 2;
  int e = idx4 >> 7;
  int ci = cols[e];
  float cntf = (float)nodeCnt[ci*16];
  float nel = fmaxf(cntf * (float)HH, 1.0f);
  float mu = sums[ci]/nel;
  float var = sums[16+ci]/nel - mu*mu;
  float rs = 1.0f/sqrtf(var+EPSF);
  float4 h = *(const float4*)(hcBuf + idx4);
  float4 o;
  o.x = (h.x-mu)*rs; o.y = (h.y-mu)*rs; o.z = (h.z-mu)*rs; o.w = (h.w-mu)*rs;
  *(float4*)(out + idx4) = o;
}

extern "C" void kernel_launch(void* const* d_in, const int* in_sizes, int n_in,
                              void* d_out, int out_size, void* d_ws, size_t ws_size,
                              hipStream_t stream){
  const float* X    = (const float*)d_in[0];
  const float* W1   = (const float*)d_in[1];
  const float* b1   = (const float*)d_in[2];
  const float* ln_g = (const float*)d_in[3];
  const float* ln_b = (const float*)d_in[4];
  const float* W2   = (const float*)d_in[5];
  const float* b2   = (const float*)d_in[6];
  const float* Wl   = (const float*)d_in[7];
  const float* bl   = (const float*)d_in[8];
  const float* Wr   = (const float*)d_in[9];
  float* ws = (float*)d_ws;
  float* F      = ws + OFF_F;
  float* cnt    = ws + OFF_CNT;
  float* sums   = ws + OFF_SUMS;
  int*   nodeCnt= (int*)(ws + OFF_NCNT);
  int*   cols   = (int*)(ws + OFF_COLS);
  int*   ranks  = (int*)(ws + OFF_RANKS);
  float* fiSel  = ws + OFF_FISEL;
  int*   nodeList=(int*)(ws + OFF_NLIST);
  float* UP     = ws + OFF_UP;
  float* agg    = ws + OFF_AGG;
  float* hcBuf  = ws + OFF_HC;
  _Float16* hbase = (_Float16*)(ws + OFF_HALF);
  float* out    = (float*)d_out;

  int cvtGrid = (ZERO_FLOATS > CVT_TOTAL ? ZERO_FLOATS : CVT_TOTAL + 255) / 256 + 1;
  k_cvt    <<<dim3(cvtGrid), dim3(256), 0, stream>>>(W1, Wl, Wr, hbase, ws);
  k_fusedA <<<dim3(NN*CCC/MT), dim3(256), 0, stream>>>(X, hbase+HOFF_W1H, hbase+HOFF_W1L,
                                                       b1, ln_g, ln_b, W2, b2,
                                                       cols, ranks, fiSel, nodeCnt, nodeList,
                                                       F, cnt);
  k_pairs  <<<dim3(105,16), dim3(128), 0, stream>>>(F, UP);
  k_singles<<<dim3(15,16), dim3(128), 0, stream>>>(UP);
  k_as     <<<dim3(NCLS,16), dim3(128), 0, stream>>>(F, UP, cnt, agg);
  k_aggwl  <<<dim3((NCLS+MT-1)/MT,16), dim3(256), 0, stream>>>(agg, hbase+HOFF_WLH, bl);
  k_hc2    <<<dim3((NN/MT),16), dim3(256), 0, stream>>>(X, hbase+HOFF_WRH, ranks, fiSel,
                                                        nodeCnt, nodeList, agg, hcBuf, sums);
  k_out    <<<dim3(NN*KTOP*HH/1024), dim3(256), 0, stream>>>(hcBuf, cols, nodeCnt, sums, out);
}